// Round 4
// baseline (7575.130 us; speedup 1.0000x reference)
//
#include <hip/hip_runtime.h>
#include <math.h>

// PointerNet: B=256, Li=512, Lo=128, C=16, E=128, H=256
// v10 = v6 (round-0 verified, 7553us) with PURE REORDERING — no new
// primitives, no new builtins, no scope changes, no extra params:
//  - Pre-publish slice computes gates only; the W1 slice runs after the
//    h-flag store (off the publish critical path).
//  - encp reductions are done by waves 4-5 (tid 256..383, otherwise idle)
//    after the next POLL's barrier, so the polling wave (tid<64) starts
//    each poll immediately after the flag store. Deferred-by-one-half
//    dataflow; every lds_pw write->read pair is barrier-separated.
//  - encp coverage: rows 0..509 deferred in-loop, row 510 at boundary
//    (rows 8-15) / in-loop (rows 0-7), row 511 full at boundary.
// All memory/sync primitives byte-identical to v6. Decoder unchanged.

typedef float vf4 __attribute__((ext_vector_type(4)));

__device__ __forceinline__ float dot4(vf4 a, vf4 b) {
  return a.x * b.x + a.y * b.y + a.z * b.z + a.w * b.w;
}

__device__ __forceinline__ float tanh_fast(float x) {
  float e = __expf(2.0f * x);
  return 1.0f - 2.0f * __builtin_amdgcn_rcpf(e + 1.0f);
}

__device__ __forceinline__ vf4 ld1_sc1(const vf4* p) {
  vf4 v;
  asm volatile("global_load_dwordx4 %0, %1, off sc0 sc1\n\ts_waitcnt vmcnt(0)"
               : "=v"(v) : "v"(p) : "memory");
  return v;
}

__device__ __forceinline__ void ld2_sc1(const vf4* p0, const vf4* p1, vf4& v0, vf4& v1) {
  asm volatile(
      "global_load_dwordx4 %0, %2, off sc0 sc1\n\t"
      "global_load_dwordx4 %1, %3, off sc0 sc1\n\t"
      "s_waitcnt vmcnt(0)"
      : "=&v"(v0), "=&v"(v1) : "v"(p0), "v"(p1) : "memory");
}

#define AL(p) __hip_atomic_load((p), __ATOMIC_RELAXED, __HIP_MEMORY_SCOPE_AGENT)
#define AS(p, v) __hip_atomic_store((p), (v), __ATOMIC_RELAXED, __HIP_MEMORY_SCOPE_AGENT)
#define DRAIN() asm volatile("s_waitcnt vmcnt(0)" ::: "memory")

__global__ __launch_bounds__(512, 2) void pointer_net_kernel(
    const float* __restrict__ inputs,  // [256,512,16]
    const float* __restrict__ emb_W,   // [128,16]
    const float* __restrict__ emb_b,   // [128]
    const float* __restrict__ eWih,    // [1024,128]
    const float* __restrict__ eWhh,    // [1024,256]
    const float* __restrict__ eb,      // [1024]
    const float* __restrict__ dWih,    // [1024,128]
    const float* __restrict__ dWhh,    // [1024,256]
    const float* __restrict__ db,      // [1024]
    const float* __restrict__ W1,      // [256,256]
    const float* __restrict__ W2,      // [256,256]
    const float* __restrict__ Vv,      // [256]
    const float* __restrict__ d0,      // [128]
    float* __restrict__ out,           // logits [256,512,128] | pointers [256,128]
    float* __restrict__ encp,          // ws: [256,512,256] fp32
    float* __restrict__ ring,          // ws: [16 groups][4 slots][16 rows][256]
    int* __restrict__ hflags,          // ws: [16 groups][2 halves][16]
    unsigned int* __restrict__ pflags) // ws: [16][16] packed (j<<16)|ptr
{
  __shared__ float lds_h[16 * 260];     // h tile, padded rows
  __shared__ float lds_part[256 * 68];  // gate partials [bb*16+ks][sdl*4+g]
  __shared__ float lds_pw[256 * 17];    // W1 partials  [bb*16+ks][sdl]
  __shared__ float lds_wx[2][1024];     // fused input weights enc/dec
  __shared__ float lds_sc[512];
  __shared__ float lds_de[512];         // W2-dot halves [hf][256]

  const int tid = threadIdx.x;
  const int B = blockIdx.x;
  // XCD-co-locating swizzle (speed-only)
  const int bi = ((B & 7) << 1) | (B >> 7);  // group 0..15
  const int dj = (B >> 3) & 15;              // slot in group
  const int bl = tid >> 4, dl = tid & 15;    // cell role (tid<256)
  const int b = (bi << 4) + bl;
  const int d = (dj << 4) + dl;
  const int b_own = (bi << 4) + dj;
  const int lane = tid & 63;
  const int wv = tid >> 6;
  // slice roles
  const int sdl = tid & 15, sks = (tid >> 4) & 15;
  const int sb4 = (tid >> 8) << 2;   // 4-bb span within a half
  const int sbh8 = (tid >> 8) << 3;  // 8-bb span for full-tile slices

  int* fgA = hflags + (bi << 5);
  int* fgB = fgA + 16;
  unsigned int* pfg = pflags + (bi << 4);
  float* ring_g = ring + ((size_t)bi << 14);

  asm volatile("buffer_inv sc1\n\ts_waitcnt vmcnt(0)" ::: "memory");

  // ---- weight slices into VGPRs: 4 gate rows + W1 row, k-slice sks*16 ----
  vf4 wreg[16], w1reg[4];
  {
    const int k0 = sks << 4;
#pragma unroll
    for (int g = 0; g < 4; ++g) {
      const float* wr = eWhh + ((size_t)((g << 8) + (dj << 4) + sdl)) * 256 + k0;
#pragma unroll
      for (int q = 0; q < 4; ++q) wreg[(g << 2) + q] = *(const vf4*)(wr + (q << 2));
    }
    const float* w1r = W1 + ((size_t)(dj << 4) + sdl) * 256 + k0;
#pragma unroll
    for (int q = 0; q < 4; ++q) w1reg[q] = *(const vf4*)(w1r + (q << 2));
  }

  // ---- fused input weights (Wih @ emb_W) for this WG's 16 dims ----
  for (int idx = tid; idx < 1024; idx += 512) {
    int c = idx >> 6, jj = idx & 63;
    int j = ((jj & 3) << 8) + (dj << 4) + (jj >> 2);
    float se = 0.f, sd = 0.f;
    const float* er = eWih + (size_t)j * 128;
    const float* dr = dWih + (size_t)j * 128;
    for (int e = 0; e < 128; ++e) {
      float ew = emb_W[(e << 4) + c];
      se += er[e] * ew;
      sd += dr[e] * ew;
    }
    lds_wx[0][idx] = se;
    lds_wx[1][idx] = sd;
  }
  float benr[4] = {0, 0, 0, 0}, dber[4] = {0, 0, 0, 0},
        dbemb[4] = {0, 0, 0, 0}, g0r[4] = {0, 0, 0, 0};
  if (tid < 256) {
    for (int g = 0; g < 4; ++g) {
      int j = (g << 8) + d;
      const float* er = eWih + (size_t)j * 128;
      const float* dr = dWih + (size_t)j * 128;
      float s1 = 0.f, s2 = 0.f, s3 = 0.f;
      for (int e = 0; e < 128; ++e) {
        s1 += er[e] * emb_b[e];
        s2 += dr[e] * emb_b[e];
        s3 += dr[e] * d0[e];
      }
      benr[g] = eb[j] + s1;
      dber[g] = db[j];
      dbemb[g] = s2;
      g0r[g] = s3;
    }
  }
  vf4 v4a = *((const vf4*)Vv + lane);
  float c_reg = 0.0f;
  __syncthreads();

#define POLL(fb, u)                                                              \
  if (tid < 64) {                                                                \
    const int* fp = (fb) + (tid & 15);                                           \
    for (;;) {                                                                   \
      int f;                                                                     \
      asm volatile("global_load_dword %0, %1, off sc0 sc1\n\ts_waitcnt vmcnt(0)" \
                   : "=v"(f) : "v"(fp) : "memory");                              \
      if (__ballot(f >= (u)) == ~0ull) break;                                    \
      __builtin_amdgcn_s_sleep(1);                                               \
    }                                                                            \
  }                                                                              \
  __syncthreads();

#define LOAD_HALF(slot, half)                                                    \
  {                                                                              \
    int grow = ((half) << 3) + (tid >> 6);                                       \
    int col = (tid & 63) << 2;                                                   \
    vf4 v = ld1_sc1((const vf4*)(ring_g + ((size_t)(slot) << 12) + (grow << 8) + col)); \
    *(vf4*)(lds_h + grow * 260 + col) = v;                                       \
  }                                                                              \
  __syncthreads();

#define LOAD_FULL(slot)                                                          \
  {                                                                              \
    int r0 = tid >> 6, col = (tid & 63) << 2;                                    \
    const float* base = ring_g + ((size_t)(slot) << 12);                         \
    vf4 v0, v1;                                                                  \
    ld2_sc1((const vf4*)(base + (r0 << 8) + col),                                \
            (const vf4*)(base + ((r0 + 8) << 8) + col), v0, v1);                 \
    *(vf4*)(lds_h + r0 * 260 + col) = v0;                                        \
    *(vf4*)(lds_h + (r0 + 8) * 260 + col) = v1;                                  \
  }                                                                              \
  __syncthreads();

#define SLICE_BODY(bb, do_g, do_w)                                               \
  {                                                                              \
    const float* hb = lds_h + (bb)*260 + (sks << 4);                             \
    vf4 h0 = *(const vf4*)(hb);                                                  \
    vf4 h1 = *(const vf4*)(hb + 4);                                              \
    vf4 h2 = *(const vf4*)(hb + 8);                                              \
    vf4 h3 = *(const vf4*)(hb + 12);                                             \
    int r = ((bb) << 4) + sks;                                                   \
    if (do_g) {                                                                  \
      vf4 s;                                                                     \
      s.x = dot4(h0, wreg[0]) + dot4(h1, wreg[1]) + dot4(h2, wreg[2]) +          \
            dot4(h3, wreg[3]);                                                   \
      s.y = dot4(h0, wreg[4]) + dot4(h1, wreg[5]) + dot4(h2, wreg[6]) +          \
            dot4(h3, wreg[7]);                                                   \
      s.z = dot4(h0, wreg[8]) + dot4(h1, wreg[9]) + dot4(h2, wreg[10]) +         \
            dot4(h3, wreg[11]);                                                  \
      s.w = dot4(h0, wreg[12]) + dot4(h1, wreg[13]) + dot4(h2, wreg[14]) +       \
            dot4(h3, wreg[15]);                                                  \
      *(vf4*)(lds_part + r * 68 + (sdl << 2)) = s;                               \
    }                                                                            \
    if (do_w) {                                                                  \
      lds_pw[r * 17 + sdl] = dot4(h0, w1reg[0]) + dot4(h1, w1reg[1]) +           \
                             dot4(h2, w1reg[2]) + dot4(h3, w1reg[3]);            \
    }                                                                            \
  }

#define SLICE_HALF(half, do_g, do_w)                                             \
  for (int q = 0; q < 4; ++q) SLICE_BODY(((half) << 3) + sb4 + q, do_g, do_w)

#define SLICE_FULL(do_g, do_w)                                                   \
  for (int q = 0; q < 8; ++q) SLICE_BODY(sbh8 + q, do_g, do_w)

#define RED_GATES(a0, a1, a2, a3)                                                \
  _Pragma("unroll") for (int ks = 0; ks < 16; ++ks) {                            \
    vf4 p = *(const vf4*)(lds_part + ((bl << 4) + ks) * 68 + (dl << 2));         \
    a0 += p.x; a1 += p.y; a2 += p.z; a3 += p.w;                                  \
  }

#define WX_ADD(sel, xp, a0, a1, a2, a3)                                          \
  for (int c = 0; c < 16; c += 4) {                                              \
    vf4 xv = *(const vf4*)((xp) + c);                                            \
    vf4 wx0 = *(const vf4*)(&lds_wx[sel][((c + 0) << 6) + (dl << 2)]);           \
    vf4 wx1 = *(const vf4*)(&lds_wx[sel][((c + 1) << 6) + (dl << 2)]);           \
    vf4 wx2 = *(const vf4*)(&lds_wx[sel][((c + 2) << 6) + (dl << 2)]);           \
    vf4 wx3 = *(const vf4*)(&lds_wx[sel][((c + 3) << 6) + (dl << 2)]);           \
    a0 += xv.x * wx0.x + xv.y * wx1.x + xv.z * wx2.x + xv.w * wx3.x;             \
    a1 += xv.x * wx0.y + xv.y * wx1.y + xv.z * wx2.y + xv.w * wx3.y;             \
    a2 += xv.x * wx0.z + xv.y * wx1.z + xv.z * wx2.z + xv.w * wx3.z;             \
    a3 += xv.x * wx0.w + xv.y * wx1.w + xv.z * wx2.w + xv.w * wx3.w;             \
  }

#define ACT_PUB(a0, a1, a2, a3, slot)                                            \
  {                                                                              \
    float ig = 1.0f / (1.0f + expf(-(a0)));                                      \
    float fg = 1.0f / (1.0f + expf(-(a1)));                                      \
    float gg = tanhf(a2);                                                        \
    float og = 1.0f / (1.0f + expf(-(a3)));                                      \
    c_reg = fg * c_reg + ig * gg;                                                \
    float hn = og * tanhf(c_reg);                                                \
    AS(ring_g + ((size_t)(slot) << 12) + (bl << 8) + d, hn);                     \
  }

  // =================== ENCODER t=0 (no tile) ===================
  {
    if (tid < 256) {
      float a0 = benr[0], a1 = benr[1], a2 = benr[2], a3 = benr[3];
      const float* xp = inputs + (size_t)((b << 9) << 4);
      WX_ADD(0, xp, a0, a1, a2, a3);
      ACT_PUB(a0, a1, a2, a3, 1);
    }
    DRAIN();
    __syncthreads();
    if (tid == 0) { AS(fgA + dj, 1); AS(fgB + dj, 1); }
  }

  // =================== ENCODER t=1..511 ===================
  for (int t = 1; t < 512; ++t) {
    float ax0 = 0.f, ax1 = 0.f, ax2 = 0.f, ax3 = 0.f;
    if (tid < 256) {
      ax0 = benr[0]; ax1 = benr[1]; ax2 = benr[2]; ax3 = benr[3];
      const float* xp = inputs + (size_t)(((b << 9) + t) << 4);
      WX_ADD(0, xp, ax0, ax1, ax2, ax3);
    }

    // ---- half A ----
    POLL(fgA, t);
    if (t > 1 && tid >= 256 && tid < 384) {
      // deferred encp-B: W1*h(t-2) rows 8-15 -> encp row t-2
      // (lds_pw rows 128-255 written at end of iter t-1; ordered by POLL sync)
      int tq = tid - 256;
      int blq = 8 + (tq >> 4);
      float ev = 0.f;
#pragma unroll
      for (int ks = 0; ks < 16; ++ks) ev += lds_pw[((blq << 4) + ks) * 17 + (tq & 15)];
      AS(encp + ((((size_t)((bi << 4) + blq)) << 9) + (t - 2) << 8) + d, ev);
    }
    LOAD_HALF(t & 3, 0);
    SLICE_HALF(0, 1, 0);              // gates only: publish ASAP
    __syncthreads();
    if (tid < 128) {
      RED_GATES(ax0, ax1, ax2, ax3);
      ACT_PUB(ax0, ax1, ax2, ax3, (t + 1) & 3);
    }
    DRAIN();
    __syncthreads();
    if (tid == 0) AS(fgA + dj, t + 1);
    SLICE_HALF(0, 0, 1);              // pw-A: W1 on h(t-1) rows 0-7, off critical path

    // ---- half B ----
    POLL(fgB, t);                     // sync orders pw-A writes before the read below
    if (tid >= 256 && tid < 384) {
      // encp-A: W1*h(t-1) rows 0-7 -> encp row t-1
      int tq = tid - 256;
      int blq = tq >> 4;
      float ev = 0.f;
#pragma unroll
      for (int ks = 0; ks < 16; ++ks) ev += lds_pw[((blq << 4) + ks) * 17 + (tq & 15)];
      AS(encp + ((((size_t)((bi << 4) + blq)) << 9) + (t - 1) << 8) + d, ev);
    }
    LOAD_HALF(t & 3, 1);
    SLICE_HALF(1, 1, 0);
    __syncthreads();
    if (tid >= 128 && tid < 256) {
      RED_GATES(ax0, ax1, ax2, ax3);
      ACT_PUB(ax0, ax1, ax2, ax3, (t + 1) & 3);
    }
    DRAIN();
    __syncthreads();
    if (tid == 0) AS(fgB + dj, t + 1);
    SLICE_HALF(1, 0, 1);              // pw-B: W1 on h(t-1) rows 8-15, reduced next iter
  }

  // ========== boundary: h(511) tile, encp rows 510/511, dec weights ==========
  POLL(fgA, 512);
  POLL(fgB, 512);
  if (tid >= 256 && tid < 384) {
    // deferred encp-B from t=511: W1*h(510) rows 8-15 -> encp row 510
    int tq = tid - 256;
    int blq = 8 + (tq >> 4);
    float ev = 0.f;
#pragma unroll
    for (int ks = 0; ks < 16; ++ks) ev += lds_pw[((blq << 4) + ks) * 17 + (tq & 15)];
    AS(encp + ((((size_t)((bi << 4) + blq)) << 9) + 510 << 8) + d, ev);
  }
  LOAD_FULL(0);  // 512 & 3 == 0 -> h(511); barrier separates pw read above from write below
  SLICE_FULL(0, 1);                   // W1 on h(511), all 16 rows
  __syncthreads();
  if (tid < 256) {
    float ev = 0.f;
#pragma unroll
    for (int ks = 0; ks < 16; ++ks) ev += lds_pw[((bl << 4) + ks) * 17 + dl];
    AS(encp + (((size_t)((b << 9) + 511)) << 8) + d, ev);
  }
  {
    const int k0 = sks << 4;
#pragma unroll
    for (int g = 0; g < 4; ++g) {
      const float* wr = dWhh + ((size_t)((g << 8) + (dj << 4) + sdl)) * 256 + k0;
#pragma unroll
      for (int q = 0; q < 4; ++q) wreg[(g << 2) + q] = *(const vf4*)(wr + (q << 2));
    }
  }
  SLICE_FULL(1, 0);                   // gate partials for decoder j=0
  __syncthreads();

  // =================== DECODER j = 0..127 ===================
  for (int j = 0; j < 128; ++j) {
    const int u = 513 + j;
    // ---- stage A: gates from saved partials; cell update; publish ----
    if (tid < 256) {
      float a0 = dber[0], a1 = dber[1], a2 = dber[2], a3 = dber[3];
      RED_GATES(a0, a1, a2, a3);
      if (j == 0) {
        a0 += g0r[0]; a1 += g0r[1]; a2 += g0r[2]; a3 += g0r[3];
      } else {
        a0 += dbemb[0]; a1 += dbemb[1]; a2 += dbemb[2]; a3 += dbemb[3];
        unsigned int pf;
        for (;;) {
          pf = AL(pfg + bl);
          if ((pf >> 16) == (unsigned int)(j - 1)) break;
          __builtin_amdgcn_s_sleep(1);
        }
        const float* xp = inputs + (size_t)(((b << 9) + (int)(pf & 0xffff)) << 4);
        WX_ADD(1, xp, a0, a1, a2, a3);
      }
      ACT_PUB(a0, a1, a2, a3, u & 3);
    }
    DRAIN();
    __syncthreads();
    if (tid == 0) AS(fgA + dj, u);

    POLL(fgA, u);
    LOAD_FULL(u & 3);

    // early encp prefetch (independent of h) — overlaps the W2 dot
    const vf4* bse = (const vf4*)(encp + ((size_t)b_own << 17));
    vf4 A[8], Bv[8];
#pragma unroll
    for (int jj = 0; jj < 8; ++jj)
      A[jj] = bse[((size_t)(wv + (jj << 3)) << 6) + lane];

    // ---- dec_term = row dj @ W2^T, split over 512 threads ----
    {
      const int d2 = tid & 255, hf = tid >> 8;
      const float* hrow = lds_h + dj * 260 + (hf << 7);
      const float* w2r = W2 + (size_t)d2 * 256 + (hf << 7);
      float a = 0.f;
      for (int k = 0; k < 128; k += 4) {
        vf4 h4 = *(const vf4*)(hrow + k);
        vf4 q = *(const vf4*)(w2r + k);
        a += dot4(h4, q);
      }
      lds_de[(hf << 8) + d2] = a;
    }
    __syncthreads();

    // ---- scores + argmax ----
    {
      vf4 p0 = *((const vf4*)lds_de + lane);
      vf4 p1 = *((const vf4*)(lds_de + 256) + lane);
      vf4 d4; d4.x = p0.x + p1.x; d4.y = p0.y + p1.y;
              d4.z = p0.z + p1.z; d4.w = p0.w + p1.w;
      for (int ch = 0; ch < 8; ++ch) {
        if (ch < 7) {
#pragma unroll
          for (int jj = 0; jj < 8; ++jj)
            Bv[jj] = bse[((size_t)(wv + (((ch + 1) * 8 + jj) << 3)) << 6) + lane];
        }
#pragma unroll
        for (int jj = 0; jj < 8; ++jj) {
          int li = wv + (((ch << 3) + jj) << 3);
          vf4 e4 = A[jj];
          float s = v4a.x * tanh_fast(e4.x + d4.x)
                  + v4a.y * tanh_fast(e4.y + d4.y)
                  + v4a.z * tanh_fast(e4.z + d4.z)
                  + v4a.w * tanh_fast(e4.w + d4.w);
#pragma unroll
          for (int off = 32; off; off >>= 1) s += __shfl_down(s, off);
          if (lane == 0) lds_sc[li] = s;
        }
#pragma unroll
        for (int jj = 0; jj < 8; ++jj) A[jj] = Bv[jj];
      }
      __syncthreads();

      __builtin_nontemporal_store(lds_sc[tid],
          &out[(size_t)(((b_own << 9) + tid) << 7) + j]);

      if (tid < 64) {
        float bs = -3.402823466e38f;
        int bix = 0;
        for (int i = 0; i < 8; ++i) {
          int idx = (i << 6) + tid;
          float s = lds_sc[idx];
          if (s > bs || (s == bs && idx < bix)) { bs = s; bix = idx; }
        }
#pragma unroll
        for (int off = 32; off; off >>= 1) {
          float os = __shfl_down(bs, off);
          int oi = __shfl_down(bix, off);
          if (os > bs || (os == bs && oi < bix)) { bs = os; bix = oi; }
        }
        if (tid == 0) {
          AS(pfg + dj, ((unsigned int)j << 16) | (unsigned int)bix);
          __builtin_nontemporal_store((float)bix,
              &out[(size_t)16777216 + (b_own << 7) + j]);
        }
      }
    }

    // ---- gate partials for j+1 (after ptr publish: off critical path) ----
    if (j < 127) {
      SLICE_FULL(1, 0);
      __syncthreads();
    }
  }
#undef POLL
#undef LOAD_HALF
#undef LOAD_FULL
#undef SLICE_BODY
#undef SLICE_HALF
#undef SLICE_FULL
#undef RED_GATES
#undef WX_ADD
#undef ACT_PUB
}

extern "C" void kernel_launch(void* const* d_in, const int* in_sizes, int n_in,
                              void* d_out, int out_size, void* d_ws, size_t ws_size,
                              hipStream_t stream) {
  (void)in_sizes; (void)n_in; (void)out_size;
  const float* inputs = (const float*)d_in[0];
  const float* emb_W  = (const float*)d_in[1];
  const float* emb_b  = (const float*)d_in[2];
  const float* eWih   = (const float*)d_in[3];
  const float* eWhh   = (const float*)d_in[4];
  const float* eb     = (const float*)d_in[5];
  const float* dWih   = (const float*)d_in[6];
  const float* dWhh   = (const float*)d_in[7];
  const float* db     = (const float*)d_in[8];
  const float* W1     = (const float*)d_in[9];
  const float* W2     = (const float*)d_in[10];
  const float* Vv     = (const float*)d_in[11];
  const float* d0     = (const float*)d_in[12];

  float* out = (float*)d_out;
  // ws: encp [256*512*256] | ring [16*4*16*256] | hflags [512] | pflags [256]
  float* encp   = (float*)d_ws;
  float* ring   = encp + 33554432;
  int*   hflags = (int*)(ring + 262144);
  unsigned int* pflags = (unsigned int*)(hflags + 512);

  size_t need = (size_t)(33554432 + 262144 + 768) * 4;
  if (ws_size < need) return;  // fail cleanly rather than OOB

  hipLaunchKernelGGL(pointer_net_kernel, dim3(256), dim3(512), 0, stream,
                     inputs, emb_W, emb_b, eWih, eWhh, eb, dWih, dWhh, db,
                     W1, W2, Vv, d0, out, encp, ring, hflags, pflags);
}

// Round 5
// 7113.456 us; speedup vs baseline: 1.0649x; 1.0649x over previous
//
#include <hip/hip_runtime.h>
#include <math.h>

// PointerNet: B=256, Li=512, Lo=128, C=16, E=128, H=256
// v11 = v10 (verified 7575us) with FLAG-FREE, SELF-VALIDATING ring exchange:
//  - Every published h value carries a generation bit in its mantissa LSB:
//    bit = ((read_step>>2)&1). Readers load the ring tile directly and retry
//    until all lanes' LSBs match. This removes, per half-step: the publisher
//    DRAIN, the flag store, and the flag poll round trip (~2 of 3 L3 RTs).
//  - Slot-generation alternates on each ring-slot reuse (distance 4); read-
//    gating bounds inter-block skew to <=1 step, so no tag aliasing.
//  - Init: each block clears its own ring columns to the COMPLEMENT of the
//    first-read tag (slot0->0, slots1-3->1), drains, publishes an exact
//    32-bit SIG; one-time exact-match poll before the encoder. Stale values
//    from a replayed previous dispatch provably fail first-read tags.
//  - encp visibility: one-time drain+SIG handshake at encoder/decoder
//    boundary (decoder reads peers' encp columns).
//  - pflags (pointer feedback) already value-validated: unchanged.
//  - LSB tag perturbs h by ~6e-8 relative — 4 orders below the kernel's
//    accepted 3.9e-3 logit error.
// All other primitives/arithmetic identical to v10.

typedef float vf4 __attribute__((ext_vector_type(4)));

__device__ __forceinline__ float dot4(vf4 a, vf4 b) {
  return a.x * b.x + a.y * b.y + a.z * b.z + a.w * b.w;
}

__device__ __forceinline__ float tanh_fast(float x) {
  float e = __expf(2.0f * x);
  return 1.0f - 2.0f * __builtin_amdgcn_rcpf(e + 1.0f);
}

__device__ __forceinline__ vf4 ld1_sc1(const vf4* p) {
  vf4 v;
  asm volatile("global_load_dwordx4 %0, %1, off sc0 sc1\n\ts_waitcnt vmcnt(0)"
               : "=v"(v) : "v"(p) : "memory");
  return v;
}

__device__ __forceinline__ void ld2_sc1(const vf4* p0, const vf4* p1, vf4& v0, vf4& v1) {
  asm volatile(
      "global_load_dwordx4 %0, %2, off sc0 sc1\n\t"
      "global_load_dwordx4 %1, %3, off sc0 sc1\n\t"
      "s_waitcnt vmcnt(0)"
      : "=&v"(v0), "=&v"(v1) : "v"(p0), "v"(p1) : "memory");
}

#define AL(p) __hip_atomic_load((p), __ATOMIC_RELAXED, __HIP_MEMORY_SCOPE_AGENT)
#define AS(p, v) __hip_atomic_store((p), (v), __ATOMIC_RELAXED, __HIP_MEMORY_SCOPE_AGENT)
#define ASU(p, v) __hip_atomic_store((unsigned*)(p), (unsigned)(v), __ATOMIC_RELAXED, __HIP_MEMORY_SCOPE_AGENT)
#define DRAIN() asm volatile("s_waitcnt vmcnt(0)" ::: "memory")

#define OK1(x, e) ((__float_as_uint(x) & 1u) == (unsigned)(e))

#define INIT_SIG 0x5A17C0DE
#define DONE_SIG 0x5A17D00E

__global__ __launch_bounds__(512, 2) void pointer_net_kernel(
    const float* __restrict__ inputs,  // [256,512,16]
    const float* __restrict__ emb_W,   // [128,16]
    const float* __restrict__ emb_b,   // [128]
    const float* __restrict__ eWih,    // [1024,128]
    const float* __restrict__ eWhh,    // [1024,256]
    const float* __restrict__ eb,      // [1024]
    const float* __restrict__ dWih,    // [1024,128]
    const float* __restrict__ dWhh,    // [1024,256]
    const float* __restrict__ db,      // [1024]
    const float* __restrict__ W1,      // [256,256]
    const float* __restrict__ W2,      // [256,256]
    const float* __restrict__ Vv,      // [256]
    const float* __restrict__ d0,      // [128]
    float* __restrict__ out,           // logits [256,512,128] | pointers [256,128]
    float* __restrict__ encp,          // ws: [256,512,256] fp32
    float* __restrict__ ring,          // ws: [16 groups][4 slots][16 rows][256]
    int* __restrict__ hflags,          // ws: [16 groups][2 halves][16] (handshakes only)
    unsigned int* __restrict__ pflags) // ws: [16][16] packed (j<<16)|ptr
{
  __shared__ float lds_h[16 * 260];     // h tile, padded rows
  __shared__ float lds_part[256 * 68];  // gate partials [bb*16+ks][sdl*4+g]
  __shared__ float lds_pw[256 * 17];    // W1 partials  [bb*16+ks][sdl]
  __shared__ float lds_wx[2][1024];     // fused input weights enc/dec
  __shared__ float lds_sc[512];
  __shared__ float lds_de[512];         // W2-dot halves [hf][256]

  const int tid = threadIdx.x;
  const int B = blockIdx.x;
  // XCD-co-locating swizzle (speed-only)
  const int bi = ((B & 7) << 1) | (B >> 7);  // group 0..15
  const int dj = (B >> 3) & 15;              // slot in group
  const int bl = tid >> 4, dl = tid & 15;    // cell role (tid<256)
  const int b = (bi << 4) + bl;
  const int d = (dj << 4) + dl;
  const int b_own = (bi << 4) + dj;
  const int lane = tid & 63;
  const int wv = tid >> 6;
  // slice roles
  const int sdl = tid & 15, sks = (tid >> 4) & 15;
  const int sb4 = (tid >> 8) << 2;   // 4-bb span within a half
  const int sbh8 = (tid >> 8) << 3;  // 8-bb span for full-tile slices

  int* fgA = hflags + (bi << 5);   // init handshake words
  int* fgB = fgA + 16;             // encp-done handshake words
  unsigned int* pfg = pflags + (bi << 4);
  float* ring_g = ring + ((size_t)bi << 14);

  asm volatile("buffer_inv sc1\n\ts_waitcnt vmcnt(0)" ::: "memory");

  // ---- ring init: clear OWN columns to complement of first-read tag ----
  // slot 0 first read at step 4 (tag 1) -> clear 0; slots 1-3 first read at
  // steps 1-3 (tag 0) -> clear 1. Column-disjoint across blocks.
  if (tid < 256) {
#pragma unroll
    for (int s = 0; s < 4; ++s) {
      ASU(ring_g + ((size_t)s << 12) + (bl << 8) + d, (s == 0) ? 0u : 1u);
    }
  }
  DRAIN();
  __syncthreads();
  if (tid == 0) AS(fgA + dj, INIT_SIG);

  // ---- weight slices into VGPRs: 4 gate rows + W1 row, k-slice sks*16 ----
  vf4 wreg[16], w1reg[4];
  {
    const int k0 = sks << 4;
#pragma unroll
    for (int g = 0; g < 4; ++g) {
      const float* wr = eWhh + ((size_t)((g << 8) + (dj << 4) + sdl)) * 256 + k0;
#pragma unroll
      for (int q = 0; q < 4; ++q) wreg[(g << 2) + q] = *(const vf4*)(wr + (q << 2));
    }
    const float* w1r = W1 + ((size_t)(dj << 4) + sdl) * 256 + k0;
#pragma unroll
    for (int q = 0; q < 4; ++q) w1reg[q] = *(const vf4*)(w1r + (q << 2));
  }

  // ---- fused input weights (Wih @ emb_W) for this WG's 16 dims ----
  for (int idx = tid; idx < 1024; idx += 512) {
    int c = idx >> 6, jj = idx & 63;
    int j = ((jj & 3) << 8) + (dj << 4) + (jj >> 2);
    float se = 0.f, sd = 0.f;
    const float* er = eWih + (size_t)j * 128;
    const float* dr = dWih + (size_t)j * 128;
    for (int e = 0; e < 128; ++e) {
      float ew = emb_W[(e << 4) + c];
      se += er[e] * ew;
      sd += dr[e] * ew;
    }
    lds_wx[0][idx] = se;
    lds_wx[1][idx] = sd;
  }
  float benr[4] = {0, 0, 0, 0}, dber[4] = {0, 0, 0, 0},
        dbemb[4] = {0, 0, 0, 0}, g0r[4] = {0, 0, 0, 0};
  if (tid < 256) {
    for (int g = 0; g < 4; ++g) {
      int j = (g << 8) + d;
      const float* er = eWih + (size_t)j * 128;
      const float* dr = dWih + (size_t)j * 128;
      float s1 = 0.f, s2 = 0.f, s3 = 0.f;
      for (int e = 0; e < 128; ++e) {
        s1 += er[e] * emb_b[e];
        s2 += dr[e] * emb_b[e];
        s3 += dr[e] * d0[e];
      }
      benr[g] = eb[j] + s1;
      dber[g] = db[j];
      dbemb[g] = s2;
      g0r[g] = s3;
    }
  }
  vf4 v4a = *((const vf4*)Vv + lane);
  float c_reg = 0.0f;
  __syncthreads();

// exact-match one-time handshake poll
#define POLLX(fb, sig)                                                           \
  if (tid < 64) {                                                                \
    const int* fp = (fb) + (tid & 15);                                           \
    for (;;) {                                                                   \
      int f;                                                                     \
      asm volatile("global_load_dword %0, %1, off sc0 sc1\n\ts_waitcnt vmcnt(0)" \
                   : "=v"(f) : "v"(fp) : "memory");                              \
      if (__ballot(f == (sig)) == ~0ull) break;                                  \
      __builtin_amdgcn_s_sleep(8);                                               \
    }                                                                            \
  }                                                                              \
  __syncthreads();

// parity-validated tile loads: retry until all LSBs carry the expected tag
#define PLOAD_HALF(slot, half, e)                                                \
  {                                                                              \
    int grow = ((half) << 3) + wv;                                               \
    int col = lane << 2;                                                         \
    const vf4* tp = (const vf4*)(ring_g + ((size_t)(slot) << 12) + (grow << 8) + col); \
    for (;;) {                                                                   \
      vf4 v = ld1_sc1(tp);                                                       \
      bool ok = OK1(v.x, e) && OK1(v.y, e) && OK1(v.z, e) && OK1(v.w, e);        \
      if (__ballot(ok) == ~0ull) {                                               \
        *(vf4*)(lds_h + grow * 260 + col) = v;                                   \
        break;                                                                   \
      }                                                                          \
      __builtin_amdgcn_s_sleep(1);                                               \
    }                                                                            \
  }                                                                              \
  __syncthreads();

#define PLOAD_FULL(slot, e)                                                      \
  {                                                                              \
    int r0 = wv, col = lane << 2;                                                \
    const float* base = ring_g + ((size_t)(slot) << 12);                         \
    const vf4* p0 = (const vf4*)(base + (r0 << 8) + col);                        \
    const vf4* p1 = (const vf4*)(base + ((r0 + 8) << 8) + col);                  \
    for (;;) {                                                                   \
      vf4 v0, v1;                                                                \
      ld2_sc1(p0, p1, v0, v1);                                                   \
      bool ok = OK1(v0.x, e) && OK1(v0.y, e) && OK1(v0.z, e) && OK1(v0.w, e) &&  \
                OK1(v1.x, e) && OK1(v1.y, e) && OK1(v1.z, e) && OK1(v1.w, e);    \
      if (__ballot(ok) == ~0ull) {                                               \
        *(vf4*)(lds_h + r0 * 260 + col) = v0;                                    \
        *(vf4*)(lds_h + (r0 + 8) * 260 + col) = v1;                              \
        break;                                                                   \
      }                                                                          \
      __builtin_amdgcn_s_sleep(1);                                               \
    }                                                                            \
  }                                                                              \
  __syncthreads();

#define SLICE_BODY(bb, do_g, do_w)                                               \
  {                                                                              \
    const float* hb = lds_h + (bb)*260 + (sks << 4);                             \
    vf4 h0 = *(const vf4*)(hb);                                                  \
    vf4 h1 = *(const vf4*)(hb + 4);                                              \
    vf4 h2 = *(const vf4*)(hb + 8);                                              \
    vf4 h3 = *(const vf4*)(hb + 12);                                             \
    int r = ((bb) << 4) + sks;                                                   \
    if (do_g) {                                                                  \
      vf4 s;                                                                     \
      s.x = dot4(h0, wreg[0]) + dot4(h1, wreg[1]) + dot4(h2, wreg[2]) +          \
            dot4(h3, wreg[3]);                                                   \
      s.y = dot4(h0, wreg[4]) + dot4(h1, wreg[5]) + dot4(h2, wreg[6]) +          \
            dot4(h3, wreg[7]);                                                   \
      s.z = dot4(h0, wreg[8]) + dot4(h1, wreg[9]) + dot4(h2, wreg[10]) +         \
            dot4(h3, wreg[11]);                                                  \
      s.w = dot4(h0, wreg[12]) + dot4(h1, wreg[13]) + dot4(h2, wreg[14]) +       \
            dot4(h3, wreg[15]);                                                  \
      *(vf4*)(lds_part + r * 68 + (sdl << 2)) = s;                               \
    }                                                                            \
    if (do_w) {                                                                  \
      lds_pw[r * 17 + sdl] = dot4(h0, w1reg[0]) + dot4(h1, w1reg[1]) +           \
                             dot4(h2, w1reg[2]) + dot4(h3, w1reg[3]);            \
    }                                                                            \
  }

#define SLICE_HALF(half, do_g, do_w)                                             \
  for (int q = 0; q < 4; ++q) SLICE_BODY(((half) << 3) + sb4 + q, do_g, do_w)

#define SLICE_FULL(do_g, do_w)                                                   \
  for (int q = 0; q < 8; ++q) SLICE_BODY(sbh8 + q, do_g, do_w)

#define RED_GATES(a0, a1, a2, a3)                                                \
  _Pragma("unroll") for (int ks = 0; ks < 16; ++ks) {                            \
    vf4 p = *(const vf4*)(lds_part + ((bl << 4) + ks) * 68 + (dl << 2));         \
    a0 += p.x; a1 += p.y; a2 += p.z; a3 += p.w;                                  \
  }

#define WX_ADD(sel, xp, a0, a1, a2, a3)                                          \
  for (int c = 0; c < 16; c += 4) {                                              \
    vf4 xv = *(const vf4*)((xp) + c);                                            \
    vf4 wx0 = *(const vf4*)(&lds_wx[sel][((c + 0) << 6) + (dl << 2)]);           \
    vf4 wx1 = *(const vf4*)(&lds_wx[sel][((c + 1) << 6) + (dl << 2)]);           \
    vf4 wx2 = *(const vf4*)(&lds_wx[sel][((c + 2) << 6) + (dl << 2)]);           \
    vf4 wx3 = *(const vf4*)(&lds_wx[sel][((c + 3) << 6) + (dl << 2)]);           \
    a0 += xv.x * wx0.x + xv.y * wx1.x + xv.z * wx2.x + xv.w * wx3.x;             \
    a1 += xv.x * wx0.y + xv.y * wx1.y + xv.z * wx2.y + xv.w * wx3.y;             \
    a2 += xv.x * wx0.z + xv.y * wx1.z + xv.z * wx2.z + xv.w * wx3.z;             \
    a3 += xv.x * wx0.w + xv.y * wx1.w + xv.z * wx2.w + xv.w * wx3.w;             \
  }

// publish h with the read-step generation bit forced into the mantissa LSB
#define ACT_PUB(a0, a1, a2, a3, slot, tagbit)                                    \
  {                                                                              \
    float ig = 1.0f / (1.0f + expf(-(a0)));                                      \
    float fg = 1.0f / (1.0f + expf(-(a1)));                                      \
    float gg = tanhf(a2);                                                        \
    float og = 1.0f / (1.0f + expf(-(a3)));                                      \
    c_reg = fg * c_reg + ig * gg;                                                \
    float hn = og * tanhf(c_reg);                                                \
    unsigned hu = (__float_as_uint(hn) & ~1u) | (unsigned)(tagbit);              \
    ASU(ring_g + ((size_t)(slot) << 12) + (bl << 8) + d, hu);                    \
  }

  // =================== ENCODER t=0 (fire-and-forget publish) ===================
  if (tid < 256) {
    float a0 = benr[0], a1 = benr[1], a2 = benr[2], a3 = benr[3];
    const float* xp = inputs + (size_t)((b << 9) << 4);
    WX_ADD(0, xp, a0, a1, a2, a3);
    ACT_PUB(a0, a1, a2, a3, 1, 0);  // h(1) -> slot 1, read-step 1 tag 0
  }

  // one-time init handshake (peers' ring clears are visible once SIG seen)
  POLLX(fgA, INIT_SIG);

  // =================== ENCODER t=1..511 ===================
  for (int t = 1; t < 512; ++t) {
    const int e = (t >> 2) & 1;            // expected tag for reads of h(t)
    const int pt = ((t + 1) >> 2) & 1;     // publish tag for h(t+1)
    float ax0 = 0.f, ax1 = 0.f, ax2 = 0.f, ax3 = 0.f;
    if (tid < 256) {
      ax0 = benr[0]; ax1 = benr[1]; ax2 = benr[2]; ax3 = benr[3];
      const float* xp = inputs + (size_t)(((b << 9) + t) << 4);
      WX_ADD(0, xp, ax0, ax1, ax2, ax3);
    }

    // ---- half A ----
    if (t > 1 && tid >= 256 && tid < 384) {
      // deferred encp-B: W1*h(t-1) rows 8-15 -> encp row t-2 (pw written end
      // of iter t-1; loop-end sync orders it)
      int tq = tid - 256;
      int blq = 8 + (tq >> 4);
      float ev = 0.f;
#pragma unroll
      for (int ks = 0; ks < 16; ++ks) ev += lds_pw[((blq << 4) + ks) * 17 + (tq & 15)];
      AS(encp + ((((size_t)((bi << 4) + blq)) << 9) + (t - 2) << 8) + d, ev);
    }
    PLOAD_HALF(t & 3, 0, e);
    SLICE_HALF(0, 1, 0);              // gates only
    __syncthreads();
    if (tid < 128) {
      RED_GATES(ax0, ax1, ax2, ax3);
      ACT_PUB(ax0, ax1, ax2, ax3, (t + 1) & 3, pt);  // fire-and-forget
    }
    SLICE_HALF(0, 0, 1);              // pw-A: W1 on h(t) rows 0-7
    __syncthreads();

    // ---- half B ----
    if (tid >= 256 && tid < 384) {
      // encp-A: W1*h(t) rows 0-7 -> encp row t-1 (pw-A written above, sync'd)
      int tq = tid - 256;
      int blq = tq >> 4;
      float ev = 0.f;
#pragma unroll
      for (int ks = 0; ks < 16; ++ks) ev += lds_pw[((blq << 4) + ks) * 17 + (tq & 15)];
      AS(encp + ((((size_t)((bi << 4) + blq)) << 9) + (t - 1) << 8) + d, ev);
    }
    PLOAD_HALF(t & 3, 1, e);
    SLICE_HALF(1, 1, 0);
    __syncthreads();
    if (tid >= 128 && tid < 256) {
      RED_GATES(ax0, ax1, ax2, ax3);
      ACT_PUB(ax0, ax1, ax2, ax3, (t + 1) & 3, pt);
    }
    SLICE_HALF(1, 0, 1);              // pw-B: W1 on h(t) rows 8-15
    __syncthreads();                  // orders pw-B for next iter's encp-B
  }

  // ========== boundary: h(512) tile, encp rows 510/511, dec weights ==========
  if (tid >= 256 && tid < 384) {
    // deferred encp-B from t=511: W1*h(511) rows 8-15 -> encp row 510
    int tq = tid - 256;
    int blq = 8 + (tq >> 4);
    float ev = 0.f;
#pragma unroll
    for (int ks = 0; ks < 16; ++ks) ev += lds_pw[((blq << 4) + ks) * 17 + (tq & 15)];
    AS(encp + ((((size_t)((bi << 4) + blq)) << 9) + 510 << 8) + d, ev);
  }
  PLOAD_FULL(0, 0);                   // h(512): slot 0, tag (512>>2)&1 = 0
  SLICE_FULL(0, 1);                   // W1 on h(512), all 16 rows
  __syncthreads();
  if (tid < 256) {
    float ev = 0.f;
#pragma unroll
    for (int ks = 0; ks < 16; ++ks) ev += lds_pw[((bl << 4) + ks) * 17 + dl];
    AS(encp + (((size_t)((b << 9) + 511)) << 8) + d, ev);
  }
  {
    const int k0 = sks << 4;
#pragma unroll
    for (int g = 0; g < 4; ++g) {
      const float* wr = dWhh + ((size_t)((g << 8) + (dj << 4) + sdl)) * 256 + k0;
#pragma unroll
      for (int q = 0; q < 4; ++q) wreg[(g << 2) + q] = *(const vf4*)(wr + (q << 2));
    }
  }
  SLICE_FULL(1, 0);                   // gate partials for decoder j=0
  DRAIN();                            // all my encp stores complete
  __syncthreads();
  if (tid == 0) AS(fgB + dj, DONE_SIG);
  POLLX(fgB, DONE_SIG);               // peers' encp complete before attention

  // =================== DECODER j = 0..127 ===================
  for (int j = 0; j < 128; ++j) {
    const int u = 513 + j;
    const int eu = (u >> 2) & 1;
    // ---- stage A: gates from saved partials; cell update; publish ----
    if (tid < 256) {
      float a0 = dber[0], a1 = dber[1], a2 = dber[2], a3 = dber[3];
      RED_GATES(a0, a1, a2, a3);
      if (j == 0) {
        a0 += g0r[0]; a1 += g0r[1]; a2 += g0r[2]; a3 += g0r[3];
      } else {
        a0 += dbemb[0]; a1 += dbemb[1]; a2 += dbemb[2]; a3 += dbemb[3];
        unsigned int pf;
        for (;;) {
          pf = AL(pfg + bl);
          if ((pf >> 16) == (unsigned int)(j - 1)) break;
          __builtin_amdgcn_s_sleep(1);
        }
        const float* xp = inputs + (size_t)(((b << 9) + (int)(pf & 0xffff)) << 4);
        WX_ADD(1, xp, a0, a1, a2, a3);
      }
      ACT_PUB(a0, a1, a2, a3, u & 3, eu);  // fire-and-forget
    }
    PLOAD_FULL(u & 3, eu);

    // early encp prefetch (independent of h) — overlaps the W2 dot
    const vf4* bse = (const vf4*)(encp + ((size_t)b_own << 17));
    vf4 A[8], Bv[8];
#pragma unroll
    for (int jj = 0; jj < 8; ++jj)
      A[jj] = bse[((size_t)(wv + (jj << 3)) << 6) + lane];

    // ---- dec_term = row dj @ W2^T, split over 512 threads ----
    {
      const int d2 = tid & 255, hf = tid >> 8;
      const float* hrow = lds_h + dj * 260 + (hf << 7);
      const float* w2r = W2 + (size_t)d2 * 256 + (hf << 7);
      float a = 0.f;
      for (int k = 0; k < 128; k += 4) {
        vf4 h4 = *(const vf4*)(hrow + k);
        vf4 q = *(const vf4*)(w2r + k);
        a += dot4(h4, q);
      }
      lds_de[(hf << 8) + d2] = a;
    }
    __syncthreads();

    // ---- scores + argmax ----
    {
      vf4 p0 = *((const vf4*)lds_de + lane);
      vf4 p1 = *((const vf4*)(lds_de + 256) + lane);
      vf4 d4; d4.x = p0.x + p1.x; d4.y = p0.y + p1.y;
              d4.z = p0.z + p1.z; d4.w = p0.w + p1.w;
      for (int ch = 0; ch < 8; ++ch) {
        if (ch < 7) {
#pragma unroll
          for (int jj = 0; jj < 8; ++jj)
            Bv[jj] = bse[((size_t)(wv + (((ch + 1) * 8 + jj) << 3)) << 6) + lane];
        }
#pragma unroll
        for (int jj = 0; jj < 8; ++jj) {
          int li = wv + (((ch << 3) + jj) << 3);
          vf4 e4 = A[jj];
          float s = v4a.x * tanh_fast(e4.x + d4.x)
                  + v4a.y * tanh_fast(e4.y + d4.y)
                  + v4a.z * tanh_fast(e4.z + d4.z)
                  + v4a.w * tanh_fast(e4.w + d4.w);
#pragma unroll
          for (int off = 32; off; off >>= 1) s += __shfl_down(s, off);
          if (lane == 0) lds_sc[li] = s;
        }
#pragma unroll
        for (int jj = 0; jj < 8; ++jj) A[jj] = Bv[jj];
      }
      __syncthreads();

      __builtin_nontemporal_store(lds_sc[tid],
          &out[(size_t)(((b_own << 9) + tid) << 7) + j]);

      if (tid < 64) {
        float bs = -3.402823466e38f;
        int bix = 0;
        for (int i = 0; i < 8; ++i) {
          int idx = (i << 6) + tid;
          float s = lds_sc[idx];
          if (s > bs || (s == bs && idx < bix)) { bs = s; bix = idx; }
        }
#pragma unroll
        for (int off = 32; off; off >>= 1) {
          float os = __shfl_down(bs, off);
          int oi = __shfl_down(bix, off);
          if (os > bs || (os == bs && oi < bix)) { bs = os; bix = oi; }
        }
        if (tid == 0) {
          AS(pfg + dj, ((unsigned int)j << 16) | (unsigned int)bix);
          __builtin_nontemporal_store((float)bix,
              &out[(size_t)16777216 + (b_own << 7) + j]);
        }
      }
    }

    // ---- gate partials for j+1 (after ptr publish: off critical path) ----
    if (j < 127) {
      SLICE_FULL(1, 0);
      __syncthreads();
    }
  }
#undef POLLX
#undef PLOAD_HALF
#undef PLOAD_FULL
#undef SLICE_BODY
#undef SLICE_HALF
#undef SLICE_FULL
#undef RED_GATES
#undef WX_ADD
#undef ACT_PUB
}

extern "C" void kernel_launch(void* const* d_in, const int* in_sizes, int n_in,
                              void* d_out, int out_size, void* d_ws, size_t ws_size,
                              hipStream_t stream) {
  (void)in_sizes; (void)n_in; (void)out_size;
  const float* inputs = (const float*)d_in[0];
  const float* emb_W  = (const float*)d_in[1];
  const float* emb_b  = (const float*)d_in[2];
  const float* eWih   = (const float*)d_in[3];
  const float* eWhh   = (const float*)d_in[4];
  const float* eb     = (const float*)d_in[5];
  const float* dWih   = (const float*)d_in[6];
  const float* dWhh   = (const float*)d_in[7];
  const float* db     = (const float*)d_in[8];
  const float* W1     = (const float*)d_in[9];
  const float* W2     = (const float*)d_in[10];
  const float* Vv     = (const float*)d_in[11];
  const float* d0     = (const float*)d_in[12];

  float* out = (float*)d_out;
  // ws: encp [256*512*256] | ring [16*4*16*256] | hflags [512] | pflags [256]
  float* encp   = (float*)d_ws;
  float* ring   = encp + 33554432;
  int*   hflags = (int*)(ring + 262144);
  unsigned int* pflags = (unsigned int*)(hflags + 512);

  size_t need = (size_t)(33554432 + 262144 + 768) * 4;
  if (ws_size < need) return;  // fail cleanly rather than OOB

  hipLaunchKernelGGL(pointer_net_kernel, dim3(256), dim3(512), 0, stream,
                     inputs, emb_W, emb_b, eWih, eWhh, eb, dWih, dWhh, db,
                     W1, W2, Vv, d0, out, encp, ring, hflags, pflags);
}